// Round 7
// baseline (78.242 us; speedup 1.0000x reference)
//
#include <hip/hip_runtime.h>

// SPH pressure-gradient segmented scatter-reduce. i is SORTED.
// R7 (= R6 minus the nontemporal builtin, which doesn't accept HIP vector
// types). Two dispatches. Edge-parallel CHUNK=8; load order: index vectors
// FIRST -> pv/p_i gathers issue early -> q/dirs streams fly concurrently with
// the gathers (one effective round-trip of latency instead of two).
// -1/rho fused into flush; prep kernel zeroes out, packs {p,V} and -1/rho.

constexpr int CHUNK = 8;

__global__ __launch_bounds__(256) void prep_kernel(
    const float* __restrict__ p,
    const float* __restrict__ V,
    const float* __restrict__ rho,
    float2*      __restrict__ pv,
    float*       __restrict__ nr,
    float2*      __restrict__ out,
    int N)
{
    int n = blockIdx.x * blockDim.x + threadIdx.x;
    if (n < N) {
        pv[n]  = make_float2(p[n], V[n]);
        nr[n]  = -1.0f / rho[n];
        out[n] = make_float2(0.0f, 0.0f);
    }
}

__global__ __launch_bounds__(256, 8) void edge_kernel(
    const int*    __restrict__ ei,
    const int*    __restrict__ ej,
    const float*  __restrict__ dirs,   // [E*2] interleaved x,y
    const float*  __restrict__ qarr,
    const float*  __restrict__ support,
    const float*  __restrict__ p_i,
    const float2* __restrict__ pv,     // packed {p, V}
    const float*  __restrict__ nr,     // -1/rho
    float*        __restrict__ acc,    // [N*2], zeroed by prep
    long long E)
{
    long long t    = blockIdx.x * (long long)blockDim.x + threadIdx.x;
    long long base = t * CHUNK;
    const int lane = threadIdx.x & 63;

    int   cur = -1;
    float ax = 0.0f, ay = 0.0f;

    if (base < E) {
        const float h    = support[0];
        const float coef = -20.0f * (7.0f / 3.14159265358979323846f) / (h * h * h);

        int ii[CHUNK], jj[CHUNK];
        int nk;

        // ---- epoch 1: index vectors only (smallest possible first hop) ----
        if (base + CHUNK <= E) {
            const int4* pi4 = (const int4*)(ei + base);
            const int4* pj4 = (const int4*)(ej + base);
            int4 ia = pi4[0], ib = pi4[1];
            int4 ja = pj4[0], jb = pj4[1];
            ii[0]=ia.x; ii[1]=ia.y; ii[2]=ia.z; ii[3]=ia.w;
            ii[4]=ib.x; ii[5]=ib.y; ii[6]=ib.z; ii[7]=ib.w;
            jj[0]=ja.x; jj[1]=ja.y; jj[2]=ja.z; jj[3]=ja.w;
            jj[4]=jb.x; jj[5]=jb.y; jj[6]=jb.z; jj[7]=jb.w;
            nk = CHUNK;
        } else {
            nk = (int)(E - base);
            #pragma unroll
            for (int k = 0; k < CHUNK; ++k) {
                ii[k] = (k < nk) ? ei[base + k] : 0;
                jj[k] = (k < nk) ? ej[base + k] : 0;
            }
        }

        // ---- epoch 2: random gathers issue immediately (the long pole) ----
        float2 pvv[CHUNK];
        float  piv[CHUNK];
        #pragma unroll
        for (int k = 0; k < CHUNK; ++k) pvv[k] = pv[jj[k]];
        #pragma unroll
        for (int k = 0; k < CHUNK; ++k) piv[k] = p_i[ii[k]];

        // ---- bulk streams: independent of the gathers, fly concurrently ----
        float qq[CHUNK], dxv[CHUNK], dyv[CHUNK];
        if (base + CHUNK <= E) {
            const float4* pq4 = (const float4*)(qarr + base);
            const float4* pd4 = (const float4*)(dirs + 2 * base);
            float4 qa = pq4[0], qb = pq4[1];
            float4 d0 = pd4[0], d1 = pd4[1], d2 = pd4[2], d3 = pd4[3];
            qq[0]=qa.x; qq[1]=qa.y; qq[2]=qa.z; qq[3]=qa.w;
            qq[4]=qb.x; qq[5]=qb.y; qq[6]=qb.z; qq[7]=qb.w;
            dxv[0]=d0.x; dyv[0]=d0.y; dxv[1]=d0.z; dyv[1]=d0.w;
            dxv[2]=d1.x; dyv[2]=d1.y; dxv[3]=d1.z; dyv[3]=d1.w;
            dxv[4]=d2.x; dyv[4]=d2.y; dxv[5]=d2.z; dyv[5]=d2.w;
            dxv[6]=d3.x; dyv[6]=d3.y; dxv[7]=d3.z; dyv[7]=d3.w;
        } else {
            #pragma unroll
            for (int k = 0; k < CHUNK; ++k) {
                qq[k]  = (k < nk) ? qarr[base + k]           : 0.0f;
                dxv[k] = (k < nk) ? dirs[2 * (base + k)]     : 0.0f;
                dyv[k] = (k < nk) ? dirs[2 * (base + k) + 1] : 0.0f;
            }
        }

        float w[CHUNK];
        #pragma unroll
        for (int k = 0; k < CHUNK; ++k) {
            float om = 1.0f - qq[k];
            w[k] = (piv[k] + pvv[k].x) * pvv[k].y * (coef * qq[k] * om * om * om);
        }

        // per-thread run-length accumulate; interior flush on segment change
        cur = ii[0];
        #pragma unroll
        for (int k = 0; k < CHUNK; ++k) {
            if (k < nk) {
                if (ii[k] != cur) {
                    float s = nr[cur];
                    atomicAdd(&acc[2 * cur],     ax * s);
                    atomicAdd(&acc[2 * cur + 1], ay * s);
                    cur = ii[k];
                    ax = 0.0f; ay = 0.0f;
                }
                ax += w[k] * dxv[k];
                ay += w[k] * dyv[k];
            }
        }
    }

    // wave-level segmented inclusive scan over (cur, ax, ay); keys sorted.
    #pragma unroll
    for (int d = 1; d < 64; d <<= 1) {
        int   oc  = __shfl_up(cur, d);
        float oax = __shfl_up(ax,  d);
        float oay = __shfl_up(ay,  d);
        if (lane >= d && oc == cur) { ax += oax; ay += oay; }
    }
    int nxt = __shfl_down(cur, 1);
    if (cur >= 0 && (lane == 63 || nxt != cur)) {
        float s = nr[cur];
        atomicAdd(&acc[2 * cur],     ax * s);
        atomicAdd(&acc[2 * cur + 1], ay * s);
    }
}

extern "C" void kernel_launch(void* const* d_in, const int* in_sizes, int n_in,
                              void* d_out, int out_size, void* d_ws, size_t ws_size,
                              hipStream_t stream)
{
    // 0:i 1:j 2:ri 3:rj 4:Vi 5:Vj 6:distances 7:radialDistances
    // 8:support 9:numParticles 10:eps 11:rhoi 12:rhoj 13:pi 14:pj
    const int*   ei      = (const int*)  d_in[0];
    const int*   ej      = (const int*)  d_in[1];
    const float* Vj      = (const float*)d_in[5];
    const float* dirs    = (const float*)d_in[6];
    const float* qarr    = (const float*)d_in[7];
    const float* support = (const float*)d_in[8];
    const float* rhoi    = (const float*)d_in[11];
    const float* p_i     = (const float*)d_in[13];
    const float* p_j     = (const float*)d_in[14];

    const long long E = in_sizes[0];
    const int       N = in_sizes[11];

    // ws layout: pv[N] float2, then nr[N] float
    float2* pv = (float2*)d_ws;
    float*  nr = (float*)((char*)d_ws + (size_t)N * sizeof(float2));

    const int block = 256;

    prep_kernel<<<(N + block - 1) / block, block, 0, stream>>>(
        p_j, Vj, rhoi, pv, nr, (float2*)d_out, N);

    const long long nthreads = (E + CHUNK - 1) / CHUNK;
    const int grid = (int)((nthreads + block - 1) / block);
    edge_kernel<<<grid, block, 0, stream>>>(
        ei, ej, dirs, qarr, support, p_i, pv, nr, (float*)d_out, E);
}

// Round 8
// 67.980 us; speedup vs baseline: 1.1510x; 1.1510x over previous
//
#include <hip/hip_runtime.h>

// SPH pressure-gradient segmented scatter-reduce. i is SORTED.
// R8 = R4's proven kernel body (unscaled atomics, separate finalize, CHUNK=8,
// packed pv gather, wave segmented scan) restructured as a PERSISTENT grid
// with a software pipeline:
//   - next chunk's index loads issued during current chunk's compute
//   - next chunk's gathers+streams issued BEFORE the current scan+flush,
//     so the DS-chain/atomic tail overlaps the next memory epoch.
// Rationale: R4/R5/R7 all ~80-110us, residency-invariant, VALU <11% ->
// latency-bound with MLP throttled by one-shot wave head/tail, not by BW.

constexpr int   CHUNK = 8;
constexpr int   BLOCK = 256;
constexpr int   GRID  = 1024;   // 4 blocks/CU on 256 CUs; ~4 chunks per thread
constexpr float PI_F  = 3.14159265358979323846f;

__global__ __launch_bounds__(BLOCK) void prep_kernel(
    const float* __restrict__ p,
    const float* __restrict__ V,
    float2*      __restrict__ pv,
    float2*      __restrict__ out,
    int N)
{
    int n = blockIdx.x * blockDim.x + threadIdx.x;
    if (n < N) {
        pv[n]  = make_float2(p[n], V[n]);
        out[n] = make_float2(0.0f, 0.0f);
    }
}

__global__ __launch_bounds__(BLOCK) void edge_kernel(
    const int*    __restrict__ ei,
    const int*    __restrict__ ej,
    const float*  __restrict__ dirs,   // [E*2] interleaved x,y
    const float*  __restrict__ qarr,
    const float*  __restrict__ support,
    const float*  __restrict__ p_i,
    const float2* __restrict__ pv,     // packed {p, V}
    float*        __restrict__ acc,    // [N*2], zeroed by prep
    long long E)
{
    const long long T   = (long long)GRID * BLOCK;      // chunk stride per iter
    const long long NC  = (E + CHUNK - 1) / CHUNK;      // chunk count
    long long c   = blockIdx.x * (long long)blockDim.x + threadIdx.x;
    const int lane = threadIdx.x & 63;
    long long wfc = c - lane;                            // wave-first chunk (uniform)

    if (wfc >= NC) return;                               // whole wave OOB (safety)

    const float h    = support[0];
    const float coef = -20.0f * (7.0f / PI_F) / (h * h * h);

    int    iiA[CHUNK], jjA[CHUNK];
    int    iiB[CHUNK], jjB[CHUNK];
    float2 pvv[CHUNK];
    float  piv[CHUNK], qq[CHUNK], dxv[CHUNK], dyv[CHUNK];

#define LOAD_IDX(cc, ii, jj)                                                   \
    do {                                                                       \
        long long b_ = (cc) * CHUNK;                                           \
        if ((cc) < NC && b_ + CHUNK <= E) {                                    \
            const int4* pi4_ = (const int4*)(ei + b_);                         \
            const int4* pj4_ = (const int4*)(ej + b_);                         \
            int4 ia_ = pi4_[0], ib_ = pi4_[1];                                 \
            int4 ja_ = pj4_[0], jb_ = pj4_[1];                                 \
            ii[0]=ia_.x; ii[1]=ia_.y; ii[2]=ia_.z; ii[3]=ia_.w;                \
            ii[4]=ib_.x; ii[5]=ib_.y; ii[6]=ib_.z; ii[7]=ib_.w;                \
            jj[0]=ja_.x; jj[1]=ja_.y; jj[2]=ja_.z; jj[3]=ja_.w;                \
            jj[4]=jb_.x; jj[5]=jb_.y; jj[6]=jb_.z; jj[7]=jb_.w;                \
        } else {                                                               \
            _Pragma("unroll")                                                  \
            for (int k_ = 0; k_ < CHUNK; ++k_) {                               \
                long long e_ = b_ + k_;                                        \
                bool ok_ = ((cc) < NC) && (e_ < E);                            \
                ii[k_] = ok_ ? ei[e_] : -1;                                    \
                jj[k_] = ok_ ? ej[e_] : 0;                                     \
            }                                                                  \
        }                                                                      \
    } while (0)

#define LOAD_GS(cc, ii, jj)                                                    \
    do {                                                                       \
        long long b_ = (cc) * CHUNK;                                           \
        _Pragma("unroll")                                                      \
        for (int k_ = 0; k_ < CHUNK; ++k_) pvv[k_] = pv[jj[k_]];               \
        _Pragma("unroll")                                                      \
        for (int k_ = 0; k_ < CHUNK; ++k_) {                                   \
            int i_ = ii[k_] < 0 ? 0 : ii[k_];                                  \
            piv[k_] = p_i[i_];                                                 \
        }                                                                      \
        if ((cc) < NC && b_ + CHUNK <= E) {                                    \
            const float4* pq4_ = (const float4*)(qarr + b_);                   \
            const float4* pd4_ = (const float4*)(dirs + 2 * b_);               \
            float4 qa_ = pq4_[0], qb_ = pq4_[1];                               \
            float4 d0_ = pd4_[0], d1_ = pd4_[1], d2_ = pd4_[2], d3_ = pd4_[3]; \
            qq[0]=qa_.x; qq[1]=qa_.y; qq[2]=qa_.z; qq[3]=qa_.w;                \
            qq[4]=qb_.x; qq[5]=qb_.y; qq[6]=qb_.z; qq[7]=qb_.w;                \
            dxv[0]=d0_.x; dyv[0]=d0_.y; dxv[1]=d0_.z; dyv[1]=d0_.w;            \
            dxv[2]=d1_.x; dyv[2]=d1_.y; dxv[3]=d1_.z; dyv[3]=d1_.w;            \
            dxv[4]=d2_.x; dyv[4]=d2_.y; dxv[5]=d2_.z; dyv[5]=d2_.w;            \
            dxv[6]=d3_.x; dyv[6]=d3_.y; dxv[7]=d3_.z; dyv[7]=d3_.w;            \
        } else {                                                               \
            _Pragma("unroll")                                                  \
            for (int k_ = 0; k_ < CHUNK; ++k_) {                               \
                long long e_ = b_ + k_;                                        \
                bool ok_ = ((cc) < NC) && (e_ < E);                            \
                qq[k_]  = ok_ ? qarr[e_]           : 0.0f;                     \
                dxv[k_] = ok_ ? dirs[2 * e_]       : 0.0f;                     \
                dyv[k_] = ok_ ? dirs[2 * e_ + 1]   : 0.0f;                     \
            }                                                                  \
        }                                                                      \
    } while (0)

    // ---- prologue: fill pipeline for the first chunk ----
    LOAD_IDX(c, iiA, jjA);
    LOAD_GS(c, iiA, jjA);

    for (;;) {
        long long cn = c + T;
        bool have_next = (wfc + T) < NC;   // wave-uniform

        // issue next chunk's index loads; in flight during compute below
        if (have_next) LOAD_IDX(cn, iiB, jjB);

        // compute w (compiler inserts vmcnt waits for pvv/piv/qq here)
        float w[CHUNK];
        #pragma unroll
        for (int k = 0; k < CHUNK; ++k) {
            float om = 1.0f - qq[k];
            w[k] = (piv[k] + pvv[k].x) * pvv[k].y * (coef * qq[k] * om * om * om);
        }

        // per-thread run-length accumulate; interior flush on segment change
        int   cur = iiA[0];
        float ax = 0.0f, ay = 0.0f;
        #pragma unroll
        for (int k = 0; k < CHUNK; ++k) {
            if (iiA[k] != cur) {
                if (cur >= 0) {
                    atomicAdd(&acc[2 * cur],     ax);
                    atomicAdd(&acc[2 * cur + 1], ay);
                }
                cur = iiA[k];
                ax = 0.0f; ay = 0.0f;
            }
            ax += w[k] * dxv[k];
            ay += w[k] * dyv[k];
        }

        // issue next chunk's gathers+streams NOW -> in flight during scan/flush
        if (have_next) LOAD_GS(cn, iiB, jjB);

        // wave-level segmented inclusive scan over (cur, ax, ay); keys sorted
        #pragma unroll
        for (int d = 1; d < 64; d <<= 1) {
            int   oc  = __shfl_up(cur, d);
            float oax = __shfl_up(ax,  d);
            float oay = __shfl_up(ay,  d);
            if (lane >= d && oc == cur) { ax += oax; ay += oay; }
        }
        int nxt = __shfl_down(cur, 1);
        if (cur >= 0 && (lane == 63 || nxt != cur)) {
            atomicAdd(&acc[2 * cur],     ax);
            atomicAdd(&acc[2 * cur + 1], ay);
        }

        if (!have_next) break;
        #pragma unroll
        for (int k = 0; k < CHUNK; ++k) { iiA[k] = iiB[k]; jjA[k] = jjB[k]; }
        c = cn;
        wfc += T;
    }

#undef LOAD_IDX
#undef LOAD_GS
}

__global__ __launch_bounds__(BLOCK) void finalize_kernel(
    float2* __restrict__ out,
    const float* __restrict__ rhoi,
    int N)
{
    int n = blockIdx.x * blockDim.x + threadIdx.x;
    if (n < N) {
        float2 a  = out[n];
        float  sc = -1.0f / rhoi[n];
        out[n] = make_float2(a.x * sc, a.y * sc);
    }
}

extern "C" void kernel_launch(void* const* d_in, const int* in_sizes, int n_in,
                              void* d_out, int out_size, void* d_ws, size_t ws_size,
                              hipStream_t stream)
{
    // 0:i 1:j 2:ri 3:rj 4:Vi 5:Vj 6:distances 7:radialDistances
    // 8:support 9:numParticles 10:eps 11:rhoi 12:rhoj 13:pi 14:pj
    const int*   ei      = (const int*)  d_in[0];
    const int*   ej      = (const int*)  d_in[1];
    const float* Vj      = (const float*)d_in[5];
    const float* dirs    = (const float*)d_in[6];
    const float* qarr    = (const float*)d_in[7];
    const float* support = (const float*)d_in[8];
    const float* rhoi    = (const float*)d_in[11];
    const float* p_i     = (const float*)d_in[13];
    const float* p_j     = (const float*)d_in[14];

    const long long E = in_sizes[0];
    const int       N = in_sizes[11];

    float2* pv = (float2*)d_ws;

    prep_kernel<<<(N + BLOCK - 1) / BLOCK, BLOCK, 0, stream>>>(
        p_j, Vj, pv, (float2*)d_out, N);

    edge_kernel<<<GRID, BLOCK, 0, stream>>>(
        ei, ej, dirs, qarr, support, p_i, pv, (float*)d_out, E);

    finalize_kernel<<<(N + BLOCK - 1) / BLOCK, BLOCK, 0, stream>>>(
        (float2*)d_out, rhoi, N);
}